// Round 13
// baseline (53.784 us; speedup 1.0000x reference)
//
#include <hip/hip_runtime.h>
#include <climits>
#include <cmath>

namespace {

constexpr int kHeads = 5;
constexpr int kA = 9;
constexpr int kWH = 40000;             // 200*200
constexpr int kG = 20;
constexpr int kN = kHeads * kA * kWH;  // 1,800,000
constexpr int kBlk = 256;
constexpr int kIPT = 4;                // anchors (quads) per thread
constexpr int kQuads = kWH / kIPT;     // 10000 quads per panel
constexpr int kBPP = (kQuads + kBlk - 1) / kBlk;   // 40 blocks per panel
constexpr int kPanels = kHeads * kA;   // 45
constexpr int kBlocks = kPanels * kBPP;            // 1800
constexpr int kWaves = kBlk / 64;
constexpr int kFBlk = 1024;

// Predicates (final winner-correction MUST match rpn_main's mask forms):
//   iou <  0.3  <=>  uni<=0  ||  inter - 0.3*uni < 0      (¬lt03 = unipos ∧ t3>=0)
//   iou >= 0.7  <=>  uni>0   &&  inter - 0.7*uni >= 0
//   iou >  0    <=>  uni>0   &&  inter > 0   (exact)
__device__ __forceinline__ void iou_preds(
    float bx1, float by1, float bx2, float by2, float area_b,
    float gx1, float gy1, float gx2, float gy2, float area_g,
    bool& lt03, bool& ge07, bool& pos)
{
    const float iw = fmaxf(fminf(bx2, gx2) - fmaxf(bx1, gx1), 0.0f);
    const float ih = fmaxf(fminf(by2, gy2) - fmaxf(by1, gy1), 0.0f);
    const float inter = iw * ih;
    const float uni = area_b + area_g - inter;
    const bool unipos = uni > 0.0f;
    lt03 = !unipos || (fmaf(-0.3f, uni, inter) < 0.0f);
    ge07 = unipos && (fmaf(-0.7f, uni, inter) >= 0.0f);
    pos  = unipos && (inter > 0.0f);
}

// gt constant table entry: idx in [0,128), entry 5*j+f = {x1,y1,x2,y2,area}[f]
// (area expr MUST match the final kernel's correction path)
__device__ __forceinline__ float gt_entry(const float* __restrict__ gt, int idx) {
    if (idx >= 5 * kG) return 0.0f;
    const int j = idx / 5;
    const int f = idx - 5 * j;
    if (f < 4) return gt[4 * j + f];
    return (gt[4 * j + 2] - gt[4 * j + 0]) *
           (gt[4 * j + 3] - gt[4 * j + 1]);
}

// broadcast gt constant (idx is compile-time in the unrolled loop)
__device__ __forceinline__ float rdlane(float v0, float v1, int idx) {
    const int u = (idx < 64)
        ? __builtin_amdgcn_readlane(__float_as_int(v0), idx)
        : __builtin_amdgcn_readlane(__float_as_int(v1), idx - 64);
    return __int_as_float(u);
}

__global__ __launch_bounds__(kBlk) void rpn_main(
    const float* __restrict__ cls,
    const float* __restrict__ reg,
    const float* __restrict__ gt,
    float* __restrict__ psum,
    int* __restrict__ pcnt,
    int* __restrict__ pminn,
    int* __restrict__ pwin)
{
    __shared__ int s_wwin[kWaves][kG];

    const int tid = threadIdx.x;
    const int lane = tid & 63;
    const int wv = tid >> 6;

    // per-wave register copy of the gt table (built once from global gt)
    const float vg0 = gt_entry(gt, lane);
    const float vg1 = gt_entry(gt, 64 + lane);

    // panel-major decomposition: a wave never straddles an (head,a) panel,
    // so flat index n is strictly increasing with (lane, i) among valid lanes.
    const int p = blockIdx.x / kBPP;
    const int b = blockIdx.x - p * kBPP;
    const int head = p / kA;
    const int a = p - head * kA;
    const int q = b * kBlk + tid;
    const bool valid = q < kQuads;
    const int qc = valid ? q : (kQuads - 1);
    const int wh = qc * kIPT;

    // 4 anchors per thread: wh..wh+3 (contiguous, 16B-aligned)
    const size_t rbase = (size_t)(head * (kA * 4) + a * 4) * kWH + wh;
    const float4 c0 = *(const float4*)(reg + rbase);                     // x1
    const float4 c1 = *(const float4*)(reg + rbase + (size_t)kWH);       // y1
    const float4 c2 = *(const float4*)(reg + rbase + 2 * (size_t)kWH);   // x2
    const float4 c3 = *(const float4*)(reg + rbase + 3 * (size_t)kWH);   // y2
    const size_t tbase = (size_t)(head * kA + a) * kWH + wh;
    const float4 pv = *(const float4*)(cls + tbase);   // issued early

    const float bx1[kIPT] = { c0.x, c0.y, c0.z, c0.w };
    const float by1[kIPT] = { c1.x, c1.y, c1.z, c1.w };
    const float bx2[kIPT] = { c2.x, c2.y, c2.z, c2.w };
    const float by2[kIPT] = { c3.x, c3.y, c3.z, c3.w };
    float areab[kIPT];
    #pragma unroll
    for (int i = 0; i < kIPT; ++i)
        areab[i] = (bx2[i] - bx1[i]) * (by2[i] - by1[i]);

    // n of (lane 0, i=0) in this wave; anchor (lane,i): nwbase + (lane*4+i)*kA
    const int nwbase = (head * kWH + (b * kBlk + wv * 64) * kIPT) * kA + a;
    const int n0 = (head * kWH + wh) * kA + a;   // this thread's anchor i: n0+i*kA

    const unsigned long long valid_m = __ballot(valid);

    // Hot loop: geometry + 2 fma + 4 compares (as ballots) per (j,i).
    // ALL boolean algebra on wave-uniform uint64 lane-masks -> SALU pipe.
    unsigned long long found[kIPT] = { 0ull, 0ull, 0ull, 0ull };
    unsigned long long nalw[kIPT]  = { 0ull, 0ull, 0ull, 0ull };
    int winj[kG];

    #pragma unroll
    for (int j = 0; j < kG; ++j) {
        const float gx1 = rdlane(vg0, vg1, 5 * j + 0);
        const float gy1 = rdlane(vg0, vg1, 5 * j + 1);
        const float gx2 = rdlane(vg0, vg1, 5 * j + 2);
        const float gy2 = rdlane(vg0, vg1, 5 * j + 3);
        const float ag  = rdlane(vg0, vg1, 5 * j + 4);
        unsigned long long cand[kIPT];
        #pragma unroll
        for (int i = 0; i < kIPT; ++i) {
            const float iw = fmaxf(fminf(bx2[i], gx2) - fmaxf(bx1[i], gx1), 0.0f);
            const float ih = fmaxf(fminf(by2[i], gy2) - fmaxf(by1[i], gy1), 0.0f);
            const float inter = iw * ih;
            const float uni = (areab[i] + ag) - inter;
            const float t7 = fmaf(-0.7f, uni, inter);
            const float t3 = fmaf(-0.3f, uni, inter);
            const unsigned long long u_m  = __ballot(uni > 0.0f);
            const unsigned long long i_m  = __ballot(inter > 0.0f);
            const unsigned long long t7_m = __ballot(t7 >= 0.0f);
            const unsigned long long t3_m = __ballot(t3 >= 0.0f);
            const unsigned long long pos  = u_m & i_m;       // iou > 0
            const unsigned long long ge   = u_m & t7_m;      // iou >= 0.7
            const unsigned long long nlt  = u_m & t3_m;      // ¬(iou < 0.3)
            cand[i] = pos & ~found[i] & valid_m;  // reach includes current j
            found[i] |= ge;
            nalw[i]  |= nlt;
        }
        // per-wave winner for gt j (uniform SALU): highest lane, then highest i
        int hi[kIPT];
        #pragma unroll
        for (int i = 0; i < kIPT; ++i)
            hi[i] = (cand[i] != 0ull) ? (63 - __clzll(cand[i])) : -1;
        const int maxhi = max(max(hi[0], hi[1]), max(hi[2], hi[3]));
        int w = -1;
        if (maxhi >= 0) {
            const int bi = (hi[3] == maxhi) ? 3
                         : (hi[2] == maxhi) ? 2
                         : (hi[1] == maxhi) ? 1 : 0;
            w = nwbase + (maxhi * kIPT + bi) * kA;
        }
        winj[j] = w;
    }

    if (lane == 0) {
        #pragma unroll
        for (int j = 0; j < kG; ++j) s_wwin[wv][j] = winj[j];
    }

    // per-lane extraction (once per thread)
    const float pr[kIPT] = { pv.x, pv.y, pv.z, pv.w };
    float bce = 0.0f;
    int kept = 0;
    int my_n = INT_MAX;
    #pragma unroll
    for (int i = 0; i < kIPT; ++i) {
        const bool f_i = (found[i] >> lane) & 1ull;
        const bool aw_i = !((nalw[i] >> lane) & 1ull);   // all j were lt03
        const bool k_i = valid && (f_i || aw_i);
        const float qv = f_i ? pr[i] : (1.0f - pr[i]);
        bce += k_i ? (-__logf(qv)) : 0.0f;
        kept += k_i ? 1 : 0;
        my_n = min(my_n, k_i ? (n0 + i * kA) : INT_MAX);
    }

    // wave(64) reduction of sum/cnt/min
    for (int off = 32; off > 0; off >>= 1) {
        bce += __shfl_down(bce, off);
        kept += __shfl_down(kept, off);
        const int o = __shfl_down(my_n, off);
        my_n = min(my_n, o);
    }

    __shared__ float w_sum[kWaves];
    __shared__ int w_cnt[kWaves];
    __shared__ int w_min[kWaves];
    if ((tid & 63) == 0) {
        w_sum[wv] = bce; w_cnt[wv] = kept; w_min[wv] = my_n;
    }
    __syncthreads();

    if (tid == 0) {
        float s = 0.0f; int c = 0; int mn = INT_MAX;
        #pragma unroll
        for (int w = 0; w < kWaves; ++w) {
            s += w_sum[w]; c += w_cnt[w]; mn = min(mn, w_min[w]);
        }
        psum[blockIdx.x] = s;
        pcnt[blockIdx.x] = c;
        pminn[blockIdx.x] = mn;
    }
    if (tid < kG) {
        int v = -1;
        #pragma unroll
        for (int w = 0; w < kWaves; ++w) v = max(v, s_wwin[w][tid]);
        pwin[blockIdx.x * kG + tid] = v;
    }
}

__global__ __launch_bounds__(kFBlk) void rpn_final(
    const float* __restrict__ cls,
    const float* __restrict__ reg,
    const float* __restrict__ gt,
    const float* __restrict__ psum,
    const int* __restrict__ pcnt,
    const int* __restrict__ pminn,
    const int* __restrict__ pwin,
    float* __restrict__ out)
{
    const int tid = threadIdx.x;
    constexpr int kFWaves = kFBlk / 64;

    // deterministic strided reduction over block partials
    double s = 0.0;
    int c = 0;
    int mn = INT_MAX;
    int wmax[kG];
    #pragma unroll
    for (int j = 0; j < kG; ++j) wmax[j] = -1;

    for (int b = tid; b < kBlocks; b += kFBlk) {
        s += (double)psum[b];
        c += pcnt[b];
        mn = min(mn, pminn[b]);
        const int4* pw4 = (const int4*)(pwin + (size_t)b * kG);
        #pragma unroll
        for (int v = 0; v < 5; ++v) {
            const int4 t4 = pw4[v];
            wmax[4 * v + 0] = max(wmax[4 * v + 0], t4.x);
            wmax[4 * v + 1] = max(wmax[4 * v + 1], t4.y);
            wmax[4 * v + 2] = max(wmax[4 * v + 2], t4.z);
            wmax[4 * v + 3] = max(wmax[4 * v + 3], t4.w);
        }
    }

    for (int off = 32; off > 0; off >>= 1) {
        s += __shfl_down(s, off);
        c += __shfl_down(c, off);
        const int o = __shfl_down(mn, off);
        mn = min(mn, o);
        #pragma unroll
        for (int j = 0; j < kG; ++j) {
            const int w = __shfl_down(wmax[j], off);
            wmax[j] = max(wmax[j], w);
        }
    }

    __shared__ double sd[kFWaves];
    __shared__ int scn[kFWaves], smn[kFWaves], swx[kFWaves][kG];
    if ((tid & 63) == 0) {
        const int w = tid >> 6;
        sd[w] = s; scn[w] = c; smn[w] = mn;
        #pragma unroll
        for (int j = 0; j < kG; ++j) swx[w][j] = wmax[j];
    }
    __syncthreads();

    __shared__ double sh_sum;
    __shared__ int sh_cnt, sh_mn;
    __shared__ int sh_wn[kG];
    if (tid == 0) {
        double S = 0.0; int C = 0; int M = INT_MAX;
        #pragma unroll
        for (int w = 0; w < kFWaves; ++w) {
            S += sd[w]; C += scn[w]; M = min(M, smn[w]);
        }
        sh_sum = S; sh_cnt = C; sh_mn = M;
        #pragma unroll
        for (int j = 0; j < kG; ++j) {
            int v = -1;
            for (int w = 0; w < kFWaves; ++w) v = max(v, swx[w][j]);
            sh_wn[j] = (v < 0) ? 0 : v;   // default anchor 0
        }
    }
    __syncthreads();

    // winner corrections: labels.at[winner].set(1.0) after zeroing
    double dsum = 0.0;
    int dcnt = 0;
    int wmin = INT_MAX;
    if (tid < kG) {
        const int n = sh_wn[tid];
        wmin = n;   // every winner becomes kept -> counts toward first_idx
        bool dup = false;
        for (int g2 = 0; g2 < tid; ++g2) dup |= (sh_wn[g2] == n);
        if (!dup) {
            // recompute this anchor's base label (same predicates as rpn_main!)
            const int a = n % kA;
            const int r = n / kA;
            const int wh = r % kWH;
            const int head = r / kWH;
            const float* rb = reg + (size_t)(head * (kA * 4) + a * 4) * kWH + wh;
            const float bx1 = rb[0];
            const float by1 = rb[kWH];
            const float bx2 = rb[2 * kWH];
            const float by2 = rb[3 * kWH];
            const float area_b = (bx2 - bx1) * (by2 - by1);
            bool allwrong = true; bool found = false;
            for (int j = 0; j < kG; ++j) {
                bool lt03, ge07, pos;
                iou_preds(bx1, by1, bx2, by2, area_b,
                          gt[4 * j + 0], gt[4 * j + 1], gt[4 * j + 2], gt[4 * j + 3],
                          (gt[4 * j + 2] - gt[4 * j + 0]) * (gt[4 * j + 3] - gt[4 * j + 1]),
                          lt03, ge07, pos);
                allwrong = allwrong && lt03;   // == reach-based form (R6 proof)
                found = found || ge07;
            }
            if (!found) {
                const float p = cls[(size_t)(head * kA + a) * kWH + wh];
                if (allwrong) {
                    // base label 0 (kept): swap -log(1-p) for -log(p)
                    dsum = (double)(-__logf(p)) + (double)__logf(1.0f - p);
                } else {
                    // base label -1 (not kept): becomes kept with label 1
                    dsum = (double)(-__logf(p));
                    dcnt = 1;
                }
            }
        }
    }
    for (int off = 32; off > 0; off >>= 1) {
        dsum += __shfl_down(dsum, off);
        dcnt += __shfl_down(dcnt, off);
        const int o = __shfl_down(wmin, off);
        wmin = min(wmin, o);
    }

    if (tid == 0) {
        const double total_sum = sh_sum + dsum;
        const int total_cnt = sh_cnt + dcnt;
        const int firstk = min(sh_mn, wmin);

        const float cls_loss = (float)total_sum / (float)total_cnt;

        // reg loss: first kept anchor's box vs all gts, smooth L1, mean
        const int a = firstk % kA;
        const int r = firstk / kA;
        const int wh = r % kWH;
        const int head = r / kWH;
        const float* rb = reg + (size_t)(head * (kA * 4) + a * 4) * kWH + wh;
        const float b0[4] = { rb[0], rb[kWH], rb[2 * kWH], rb[3 * kWH] };
        float rl = 0.0f;
        for (int g = 0; g < kG; ++g) {
            #pragma unroll
            for (int k = 0; k < 4; ++k) {
                const float d = fabsf(b0[k] - gt[4 * g + k]);
                rl += (d < 1.0f) ? (0.5f * d * d) : (d - 0.5f);
            }
        }
        rl /= (float)(kG * 4);

        out[0] = cls_loss / 256.0f + rl / 2400.0f;
    }
}

}  // namespace

extern "C" void kernel_launch(void* const* d_in, const int* in_sizes, int n_in,
                              void* d_out, int out_size, void* d_ws, size_t ws_size,
                              hipStream_t stream) {
    const float* cls = (const float*)d_in[0];
    const float* reg = (const float*)d_in[1];
    const float* gt  = (const float*)d_in[2];
    float* out = (float*)d_out;

    float* psum = (float*)d_ws;
    int* pcnt = (int*)(psum + kBlocks);
    int* pminn = pcnt + kBlocks;
    int* pwin = pminn + kBlocks;   // kBlocks * kG ints (16B-aligned)

    rpn_main<<<kBlocks, kBlk, 0, stream>>>(cls, reg, gt, psum, pcnt, pminn, pwin);
    rpn_final<<<1, kFBlk, 0, stream>>>(cls, reg, gt, psum, pcnt, pminn, pwin, out);
}

// Round 15
// 49.472 us; speedup vs baseline: 1.0872x; 1.0872x over previous
//
#include <hip/hip_runtime.h>
#include <climits>
#include <cmath>

namespace {

constexpr int kHeads = 5;
constexpr int kA = 9;
constexpr int kWH = 40000;             // 200*200
constexpr int kG = 20;
constexpr int kN = kHeads * kA * kWH;  // 1,800,000
constexpr int kBlk = 256;
constexpr int kIPT = 2;                // anchors (pairs) per thread
constexpr int kPairs = kWH / kIPT;     // 20000 pairs per panel
constexpr int kBPP = (kPairs + kBlk - 1) / kBlk;   // 79 blocks per panel
constexpr int kPanels = kHeads * kA;   // 45
constexpr int kBlocks = kPanels * kBPP;            // 3555
constexpr int kWaves = kBlk / 64;
constexpr int kFBlk = 1024;

// Predicates (final winner-correction MUST match rpn_main's mask forms):
//   iou <  0.3  <=>  uni<=0  ||  inter - 0.3*uni < 0      (¬lt03 = unipos ∧ t3>=0)
//   iou >= 0.7  <=>  uni>0   &&  inter - 0.7*uni >= 0
//   iou >  0    <=>  uni>0   &&  inter > 0   (exact)
__device__ __forceinline__ void iou_preds(
    float bx1, float by1, float bx2, float by2, float area_b,
    float gx1, float gy1, float gx2, float gy2, float area_g,
    bool& lt03, bool& ge07, bool& pos)
{
    const float iw = fmaxf(fminf(bx2, gx2) - fmaxf(bx1, gx1), 0.0f);
    const float ih = fmaxf(fminf(by2, gy2) - fmaxf(by1, gy1), 0.0f);
    const float inter = iw * ih;
    const float uni = area_b + area_g - inter;
    const bool unipos = uni > 0.0f;
    lt03 = !unipos || (fmaf(-0.3f, uni, inter) < 0.0f);
    ge07 = unipos && (fmaf(-0.7f, uni, inter) >= 0.0f);
    pos  = unipos && (inter > 0.0f);
}

// gt constant table entry: idx in [0,128), entry 5*j+f = {x1,y1,x2,y2,area}[f]
// (area expr MUST match the final kernel's correction path)
__device__ __forceinline__ float gt_entry(const float* __restrict__ gt, int idx) {
    if (idx >= 5 * kG) return 0.0f;
    const int j = idx / 5;
    const int f = idx - 5 * j;
    if (f < 4) return gt[4 * j + f];
    return (gt[4 * j + 2] - gt[4 * j + 0]) *
           (gt[4 * j + 3] - gt[4 * j + 1]);
}

// broadcast gt constant (idx is compile-time in the unrolled loop)
__device__ __forceinline__ float rdlane(float v0, float v1, int idx) {
    const int u = (idx < 64)
        ? __builtin_amdgcn_readlane(__float_as_int(v0), idx)
        : __builtin_amdgcn_readlane(__float_as_int(v1), idx - 64);
    return __int_as_float(u);
}

__global__ __launch_bounds__(kBlk) void rpn_main(
    const float* __restrict__ cls,
    const float* __restrict__ reg,
    const float* __restrict__ gt,
    float* __restrict__ psum,
    int* __restrict__ pcnt,
    int* __restrict__ pminn,
    int* __restrict__ pwin)
{
    __shared__ int s_wwin[kWaves][kG];

    const int tid = threadIdx.x;
    const int lane = tid & 63;
    const int wv = tid >> 6;

    // per-wave register copy of the gt table (built once from global gt)
    const float vg0 = gt_entry(gt, lane);
    const float vg1 = gt_entry(gt, 64 + lane);

    // panel-major decomposition: a wave never straddles an (head,a) panel,
    // so flat index n is strictly increasing with (lane, i) among valid lanes.
    const int p = blockIdx.x / kBPP;
    const int b = blockIdx.x - p * kBPP;
    const int head = p / kA;
    const int a = p - head * kA;
    const int q = b * kBlk + tid;
    const bool valid = q < kPairs;
    const int qc = valid ? q : (kPairs - 1);
    const int wh = qc * kIPT;

    // 2 anchors per thread: wh, wh+1 (contiguous, 8B-aligned)
    const size_t rbase = (size_t)(head * (kA * 4) + a * 4) * kWH + wh;
    const float2 c0 = *(const float2*)(reg + rbase);                     // x1
    const float2 c1 = *(const float2*)(reg + rbase + (size_t)kWH);       // y1
    const float2 c2 = *(const float2*)(reg + rbase + 2 * (size_t)kWH);   // x2
    const float2 c3 = *(const float2*)(reg + rbase + 3 * (size_t)kWH);   // y2
    const size_t tbase = (size_t)(head * kA + a) * kWH + wh;
    const float2 pv = *(const float2*)(cls + tbase);   // issued early

    const float bx1[kIPT] = { c0.x, c0.y };
    const float by1[kIPT] = { c1.x, c1.y };
    const float bx2[kIPT] = { c2.x, c2.y };
    const float by2[kIPT] = { c3.x, c3.y };
    float areab[kIPT];
    #pragma unroll
    for (int i = 0; i < kIPT; ++i)
        areab[i] = (bx2[i] - bx1[i]) * (by2[i] - by1[i]);

    // n of (lane 0, i=0) in this wave; anchor (lane,i): nwbase + (lane*2+i)*kA
    const int nwbase = (head * kWH + (b * kBlk + wv * 64) * kIPT) * kA + a;
    const int n0 = (head * kWH + wh) * kA + a;   // this thread's anchor i: n0+i*kA

    const unsigned long long valid_m = __ballot(valid);

    // Hot loop: geometry + 2 fma + 4 compares (as ballots) per (j,i).
    // ALL boolean algebra on wave-uniform uint64 lane-masks -> SALU pipe.
    unsigned long long found[kIPT] = { 0ull, 0ull };   // lanes with ge07 so far
    unsigned long long nalw[kIPT]  = { 0ull, 0ull };   // lanes with some ¬lt03
    int winj[kG];

    #pragma unroll
    for (int j = 0; j < kG; ++j) {
        const float gx1 = rdlane(vg0, vg1, 5 * j + 0);
        const float gy1 = rdlane(vg0, vg1, 5 * j + 1);
        const float gx2 = rdlane(vg0, vg1, 5 * j + 2);
        const float gy2 = rdlane(vg0, vg1, 5 * j + 3);
        const float ag  = rdlane(vg0, vg1, 5 * j + 4);
        unsigned long long cand[kIPT];
        #pragma unroll
        for (int i = 0; i < kIPT; ++i) {
            const float iw = fmaxf(fminf(bx2[i], gx2) - fmaxf(bx1[i], gx1), 0.0f);
            const float ih = fmaxf(fminf(by2[i], gy2) - fmaxf(by1[i], gy1), 0.0f);
            const float inter = iw * ih;
            const float uni = (areab[i] + ag) - inter;
            const float t7 = fmaf(-0.7f, uni, inter);
            const float t3 = fmaf(-0.3f, uni, inter);
            const unsigned long long u_m  = __ballot(uni > 0.0f);
            const unsigned long long i_m  = __ballot(inter > 0.0f);
            const unsigned long long t7_m = __ballot(t7 >= 0.0f);
            const unsigned long long t3_m = __ballot(t3 >= 0.0f);
            const unsigned long long pos  = u_m & i_m;       // iou > 0
            const unsigned long long ge   = u_m & t7_m;      // iou >= 0.7
            const unsigned long long nlt  = u_m & t3_m;      // ¬(iou < 0.3)
            cand[i] = pos & ~found[i] & valid_m;  // reach includes current j
            found[i] |= ge;
            nalw[i]  |= nlt;
        }
        // per-wave winner for gt j (uniform SALU): highest lane, then highest i
        const unsigned long long cc0 = cand[0];
        const unsigned long long cc1 = cand[1];
        int w = -1;
        if (cc0 | cc1) {
            const int hi0 = (cc0 != 0ull) ? (63 - __clzll(cc0)) : -1;
            const int hi1 = (cc1 != 0ull) ? (63 - __clzll(cc1)) : -1;
            const int sel = (hi1 >= hi0) ? (2 * hi1 + 1) : (2 * hi0);
            w = nwbase + sel * kA;
        }
        winj[j] = w;
    }

    if (lane == 0) {
        #pragma unroll
        for (int j = 0; j < kG; ++j) s_wwin[wv][j] = winj[j];
    }

    // per-lane extraction (once per thread)
    const float pr[kIPT] = { pv.x, pv.y };
    float bce = 0.0f;
    int kept = 0;
    int my_n = INT_MAX;
    #pragma unroll
    for (int i = 0; i < kIPT; ++i) {
        const bool f_i = (found[i] >> lane) & 1ull;
        const bool aw_i = !((nalw[i] >> lane) & 1ull);   // all j were lt03
        const bool k_i = valid && (f_i || aw_i);
        const float qv = f_i ? pr[i] : (1.0f - pr[i]);
        bce += k_i ? (-__logf(qv)) : 0.0f;
        kept += k_i ? 1 : 0;
        my_n = min(my_n, k_i ? (n0 + i * kA) : INT_MAX);
    }

    // wave(64) reduction of sum/cnt/min
    for (int off = 32; off > 0; off >>= 1) {
        bce += __shfl_down(bce, off);
        kept += __shfl_down(kept, off);
        const int o = __shfl_down(my_n, off);
        my_n = min(my_n, o);
    }

    __shared__ float w_sum[kWaves];
    __shared__ int w_cnt[kWaves];
    __shared__ int w_min[kWaves];
    if ((tid & 63) == 0) {
        w_sum[wv] = bce; w_cnt[wv] = kept; w_min[wv] = my_n;
    }
    __syncthreads();

    if (tid == 0) {
        float s = 0.0f; int c = 0; int mn = INT_MAX;
        #pragma unroll
        for (int w = 0; w < kWaves; ++w) {
            s += w_sum[w]; c += w_cnt[w]; mn = min(mn, w_min[w]);
        }
        psum[blockIdx.x] = s;
        pcnt[blockIdx.x] = c;
        pminn[blockIdx.x] = mn;
    }
    if (tid < kG) {
        int v = -1;
        #pragma unroll
        for (int w = 0; w < kWaves; ++w) v = max(v, s_wwin[w][tid]);
        pwin[blockIdx.x * kG + tid] = v;
    }
}

__global__ __launch_bounds__(kFBlk) void rpn_final(
    const float* __restrict__ cls,
    const float* __restrict__ reg,
    const float* __restrict__ gt,
    const float* __restrict__ psum,
    const int* __restrict__ pcnt,
    const int* __restrict__ pminn,
    const int* __restrict__ pwin,
    float* __restrict__ out)
{
    const int tid = threadIdx.x;
    constexpr int kFWaves = kFBlk / 64;

    // deterministic strided reduction over block partials
    double s = 0.0;
    int c = 0;
    int mn = INT_MAX;
    int wmax[kG];
    #pragma unroll
    for (int j = 0; j < kG; ++j) wmax[j] = -1;

    for (int b = tid; b < kBlocks; b += kFBlk) {
        s += (double)psum[b];
        c += pcnt[b];
        mn = min(mn, pminn[b]);
        const int4* pw4 = (const int4*)(pwin + (size_t)b * kG);
        #pragma unroll
        for (int v = 0; v < 5; ++v) {
            const int4 t4 = pw4[v];
            wmax[4 * v + 0] = max(wmax[4 * v + 0], t4.x);
            wmax[4 * v + 1] = max(wmax[4 * v + 1], t4.y);
            wmax[4 * v + 2] = max(wmax[4 * v + 2], t4.z);
            wmax[4 * v + 3] = max(wmax[4 * v + 3], t4.w);
        }
    }

    for (int off = 32; off > 0; off >>= 1) {
        s += __shfl_down(s, off);
        c += __shfl_down(c, off);
        const int o = __shfl_down(mn, off);
        mn = min(mn, o);
        #pragma unroll
        for (int j = 0; j < kG; ++j) {
            const int w = __shfl_down(wmax[j], off);
            wmax[j] = max(wmax[j], w);
        }
    }

    __shared__ double sd[kFWaves];
    __shared__ int scn[kFWaves], smn[kFWaves], swx[kFWaves][kG];
    if ((tid & 63) == 0) {
        const int w = tid >> 6;
        sd[w] = s; scn[w] = c; smn[w] = mn;
        #pragma unroll
        for (int j = 0; j < kG; ++j) swx[w][j] = wmax[j];
    }
    __syncthreads();

    __shared__ double sh_sum;
    __shared__ int sh_cnt, sh_mn;
    __shared__ int sh_wn[kG];
    // parallel per-gt combine (threads 0..19); serial fold only for sum/cnt/min
    if (tid < kG) {
        int v = -1;
        #pragma unroll
        for (int w = 0; w < kFWaves; ++w) v = max(v, swx[w][tid]);
        sh_wn[tid] = (v < 0) ? 0 : v;   // default anchor 0
    }
    if (tid == 0) {
        double S = 0.0; int C = 0; int M = INT_MAX;
        #pragma unroll
        for (int w = 0; w < kFWaves; ++w) {
            S += sd[w]; C += scn[w]; M = min(M, smn[w]);
        }
        sh_sum = S; sh_cnt = C; sh_mn = M;
    }
    __syncthreads();

    // winner corrections: labels.at[winner].set(1.0) after zeroing
    double dsum = 0.0;
    int dcnt = 0;
    int wmin = INT_MAX;
    if (tid < kG) {
        const int n = sh_wn[tid];
        wmin = n;   // every winner becomes kept -> counts toward first_idx
        bool dup = false;
        for (int g2 = 0; g2 < tid; ++g2) dup |= (sh_wn[g2] == n);
        if (!dup) {
            // recompute this anchor's base label (same predicates as rpn_main!)
            const int a = n % kA;
            const int r = n / kA;
            const int wh = r % kWH;
            const int head = r / kWH;
            const float* rb = reg + (size_t)(head * (kA * 4) + a * 4) * kWH + wh;
            const float bx1 = rb[0];
            const float by1 = rb[kWH];
            const float bx2 = rb[2 * kWH];
            const float by2 = rb[3 * kWH];
            const float area_b = (bx2 - bx1) * (by2 - by1);
            bool allwrong = true; bool found = false;
            for (int j = 0; j < kG; ++j) {
                bool lt03, ge07, pos;
                iou_preds(bx1, by1, bx2, by2, area_b,
                          gt[4 * j + 0], gt[4 * j + 1], gt[4 * j + 2], gt[4 * j + 3],
                          (gt[4 * j + 2] - gt[4 * j + 0]) * (gt[4 * j + 3] - gt[4 * j + 1]),
                          lt03, ge07, pos);
                allwrong = allwrong && lt03;   // == reach-based form (R6 proof)
                found = found || ge07;
            }
            if (!found) {
                const float p = cls[(size_t)(head * kA + a) * kWH + wh];
                if (allwrong) {
                    // base label 0 (kept): swap -log(1-p) for -log(p)
                    dsum = (double)(-__logf(p)) + (double)__logf(1.0f - p);
                } else {
                    // base label -1 (not kept): becomes kept with label 1
                    dsum = (double)(-__logf(p));
                    dcnt = 1;
                }
            }
        }
    }
    for (int off = 32; off > 0; off >>= 1) {
        dsum += __shfl_down(dsum, off);
        dcnt += __shfl_down(dcnt, off);
        const int o = __shfl_down(wmin, off);
        wmin = min(wmin, o);
    }

    if (tid == 0) {
        const double total_sum = sh_sum + dsum;
        const int total_cnt = sh_cnt + dcnt;
        const int firstk = min(sh_mn, wmin);

        const float cls_loss = (float)total_sum / (float)total_cnt;

        // reg loss: first kept anchor's box vs all gts, smooth L1, mean
        const int a = firstk % kA;
        const int r = firstk / kA;
        const int wh = r % kWH;
        const int head = r / kWH;
        const float* rb = reg + (size_t)(head * (kA * 4) + a * 4) * kWH + wh;
        const float b0[4] = { rb[0], rb[kWH], rb[2 * kWH], rb[3 * kWH] };
        float rl = 0.0f;
        for (int g = 0; g < kG; ++g) {
            #pragma unroll
            for (int k = 0; k < 4; ++k) {
                const float d = fabsf(b0[k] - gt[4 * g + k]);
                rl += (d < 1.0f) ? (0.5f * d * d) : (d - 0.5f);
            }
        }
        rl /= (float)(kG * 4);

        out[0] = cls_loss / 256.0f + rl / 2400.0f;
    }
}

}  // namespace

extern "C" void kernel_launch(void* const* d_in, const int* in_sizes, int n_in,
                              void* d_out, int out_size, void* d_ws, size_t ws_size,
                              hipStream_t stream) {
    const float* cls = (const float*)d_in[0];
    const float* reg = (const float*)d_in[1];
    const float* gt  = (const float*)d_in[2];
    float* out = (float*)d_out;

    float* psum = (float*)d_ws;
    int* pcnt = (int*)(psum + kBlocks);
    int* pminn = pcnt + kBlocks;
    int* pwin = pminn + kBlocks;   // kBlocks * kG ints (16B-aligned)

    rpn_main<<<kBlocks, kBlk, 0, stream>>>(cls, reg, gt, psum, pcnt, pminn, pwin);
    rpn_final<<<1, kFBlk, 0, stream>>>(cls, reg, gt, psum, pcnt, pminn, pwin, out);
}